// Round 2
// baseline (307.658 us; speedup 1.0000x reference)
//
#include <hip/hip_runtime.h>
#include <hip/hip_bf16.h>
#include <math.h>

// Problem constants (from reference): B=8, C=256, H=W=128
#define NPLANE 2048      // B*C
#define HW     16384     // H*W
#define WW     128
#define SLOPE  0.01f
#define EPS    1e-5f

// ---------------------------------------------------------------------------
// Kernel 1: per-(b,c) plane mean.  One block per plane, 256 threads.
// Memory-bound streaming read of x (134 MB).
// ---------------------------------------------------------------------------
__global__ __launch_bounds__(256) void k_plane_mean(const float* __restrict__ x,
                                                    float* __restrict__ p) {
    const int plane = blockIdx.x;
    const float4* x4 = (const float4*)(x + (size_t)plane * HW);
    float s = 0.f;
#pragma unroll
    for (int i = 0; i < 16; ++i) {
        float4 v = x4[i * 256 + threadIdx.x];
        s += (v.x + v.y) + (v.z + v.w);
    }
#pragma unroll
    for (int off = 32; off; off >>= 1) s += __shfl_down(s, off, 64);
    __shared__ float red[4];
    const int wave = threadIdx.x >> 6, lane = threadIdx.x & 63;
    if (lane == 0) red[wave] = s;
    __syncthreads();
    if (threadIdx.x == 0) {
        float t = (red[0] + red[1]) + (red[2] + red[3]);
        p[plane] = t * (1.f / (float)HW);
    }
}

// ---------------------------------------------------------------------------
// Kernel 2 (fused): attention MLP (per-block, tiny) + depthwise 3x3 conv
// + exact folded instance-norm + leaky.
//
// Algebra: y = a*conv(x) + bias;  instance-norm(y) = a*(conv - mean_c) *
// rsqrt(a^2*var_c + eps)  -- bias cancels, 'a' folds into the epilogue.
// So: pass 1 streams x computing conv stats (sum, sumsq) with a 3-row
// register sliding window (no LDS tile, no y[] array -> high occupancy);
// pass 2 recomputes conv from L2-resident data and writes the result.
// ---------------------------------------------------------------------------
__global__ __launch_bounds__(256) void k_main(const float* __restrict__ x,
                                              const float* __restrict__ w1,
                                              const float* __restrict__ w2,
                                              const float* __restrict__ rw,
                                              const float* __restrict__ p,
                                              float* __restrict__ out) {
    __shared__ float hs[64];
    __shared__ float red[8];
    __shared__ float sh_a;

    const int plane = blockIdx.x;
    const int b = plane >> 8;
    const int ch = plane & 255;

    // ---- attention: hs[j] = leaky(dot(p[b,:], w1[j,:])), 4 threads per j ----
    {
        const int j = threadIdx.x >> 2;      // 0..63
        const int part = threadIdx.x & 3;    // 0..3
        const float4* pr = (const float4*)(p + b * 256 + part * 64);
        const float4* wr = (const float4*)(w1 + j * 256 + part * 64);
        float acc = 0.f;
#pragma unroll
        for (int k = 0; k < 16; ++k) {
            float4 pv = pr[k], wv = wr[k];
            acc += pv.x * wv.x + pv.y * wv.y + pv.z * wv.z + pv.w * wv.w;
        }
        acc += __shfl_xor(acc, 1, 64);
        acc += __shfl_xor(acc, 2, 64);
        if (part == 0) hs[j] = acc > 0.f ? acc : SLOPE * acc;
    }
    __syncthreads();
    // ---- a = sigmoid(dot(w2[ch,:], hs)) : wave 0 only ----
    if (threadIdx.x < 64) {
        float v = w2[ch * 64 + threadIdx.x] * hs[threadIdx.x];
#pragma unroll
        for (int off = 32; off; off >>= 1) v += __shfl_down(v, off, 64);
        if (threadIdx.x == 0) sh_a = 1.f / (1.f + expf(-v));
    }

    // ---- per-channel conv weights (wave-uniform -> SGPRs) ----
    const float w_0 = rw[ch * 9 + 0], w_1 = rw[ch * 9 + 1], w_2 = rw[ch * 9 + 2];
    const float w_3 = rw[ch * 9 + 3], w_4 = rw[ch * 9 + 4], w_5 = rw[ch * 9 + 5];
    const float w_6 = rw[ch * 9 + 6], w_7 = rw[ch * 9 + 7], w_8 = rw[ch * 9 + 8];

    const float* xp = x + (size_t)plane * HW;
    const int c = threadIdx.x & 127;           // column
    const int r0 = (threadIdx.x >> 7) * 64;    // first row of this thread's strip

#define LOADROW(row, L, M, Q)                                          \
    do {                                                               \
        const int _r = (row);                                          \
        if (_r >= 0 && _r <= 127) {                                    \
            const float* rp = xp + _r * WW;                            \
            M = rp[c];                                                 \
            L = (c > 0)   ? rp[c - 1] : 0.f;                           \
            Q = (c < 127) ? rp[c + 1] : 0.f;                           \
        } else { L = 0.f; M = 0.f; Q = 0.f; }                          \
    } while (0)

#define CONV9() (w_0 * l0 + w_1 * m0 + w_2 * q0                        \
               + w_3 * l1 + w_4 * m1 + w_5 * q1                        \
               + w_6 * l2 + w_7 * m2 + w_8 * q2)

    // ---- pass 1: conv stats ----
    float l0, m0, q0, l1, m1, q1, l2, m2, q2;
    LOADROW(r0 - 1, l0, m0, q0);
    LOADROW(r0,     l1, m1, q1);
    float s = 0.f, sq = 0.f;
#pragma unroll 8
    for (int j = 0; j < 64; ++j) {
        LOADROW(r0 + j + 1, l2, m2, q2);
        const float conv = CONV9();
        s += conv;
        sq += conv * conv;
        l0 = l1; m0 = m1; q0 = q1;
        l1 = l2; m1 = m2; q1 = q2;
    }

    // ---- block reduce sum / sumsq ----
#pragma unroll
    for (int off = 32; off; off >>= 1) {
        s  += __shfl_down(s,  off, 64);
        sq += __shfl_down(sq, off, 64);
    }
    const int wave = threadIdx.x >> 6, lane = threadIdx.x & 63;
    if (lane == 0) { red[wave] = s; red[4 + wave] = sq; }
    __syncthreads();
    const float S  = (red[0] + red[1]) + (red[2] + red[3]);
    const float SQ = (red[4] + red[5]) + (red[6] + red[7]);
    const float mean_c = S * (1.f / (float)HW);
    const float var_c  = SQ * (1.f / (float)HW) - mean_c * mean_c;
    const float a      = sh_a;
    const float scale  = a * rsqrtf(a * a * var_c + EPS);

    // ---- pass 2: recompute conv (L2-resident), normalize, write ----
    float* op = out + (size_t)plane * HW;
    LOADROW(r0 - 1, l0, m0, q0);
    LOADROW(r0,     l1, m1, q1);
#pragma unroll 8
    for (int j = 0; j < 64; ++j) {
        LOADROW(r0 + j + 1, l2, m2, q2);
        const float conv = CONV9();
        float v = scale * (conv - mean_c);
        v = v > 0.f ? v : SLOPE * v;
        op[(r0 + j) * WW + c] = v;
        l0 = l1; m0 = m1; q0 = q1;
        l1 = l2; m1 = m2; q1 = q2;
    }
#undef LOADROW
#undef CONV9
}

// ---------------------------------------------------------------------------
extern "C" void kernel_launch(void* const* d_in, const int* in_sizes, int n_in,
                              void* d_out, int out_size, void* d_ws, size_t ws_size,
                              hipStream_t stream) {
    const float* x  = (const float*)d_in[0];
    const float* w1 = (const float*)d_in[1];   // [64,256]
    const float* w2 = (const float*)d_in[2];   // [256,64]
    const float* rw = (const float*)d_in[3];   // [256,1,3,3]
    // d_in[4] (refine_b) cancels exactly in instance norm -- unused.
    float* out = (float*)d_out;

    float* p = (float*)d_ws;        // 2048 floats

    k_plane_mean<<<NPLANE, 256, 0, stream>>>(x, p);
    k_main<<<NPLANE, 256, 0, stream>>>(x, w1, w2, rw, p, out);
}

// Round 4
// 274.795 us; speedup vs baseline: 1.1196x; 1.1196x over previous
//
#include <hip/hip_runtime.h>
#include <hip/hip_bf16.h>
#include <math.h>

// Problem constants: B=8, C=256, H=W=128
#define NPLANE 2048
#define HW     16384
#define WW     128
#define SLOPE  0.01f
#define EPS    1e-5f

typedef float v4f __attribute__((ext_vector_type(4)));  // native vec for nontemporal store

// Load one image row segment (4 cols) + left/right neighbors via cross-lane
// shuffle.  Lanes 0-31 of a wave span one full row (32*4=128 cols); lanes
// 32-63 span another row, so the lane-31/32 shuffle boundary coincides with
// the column zero-pad boundary -- one mask handles both.
__device__ __forceinline__ void load_row(const float* __restrict__ xp, int r,
                                         int c4, int lane32,
                                         float4& m, float& L, float& R) {
    int rc = r;
    if (rc < 0) rc = 0;
    if (rc > 127) rc = 127;
    const float va = (r == rc) ? 1.f : 0.f;        // zero-pad rows -1 / 128
    float4 v = *(const float4*)(xp + rc * WW + c4);
    m.x = v.x * va; m.y = v.y * va; m.z = v.z * va; m.w = v.w * va;
    L = __shfl_up(m.w, 1, 64);
    if (lane32 == 0) L = 0.f;                      // col -1 zero-pad
    R = __shfl_down(m.x, 1, 64);
    if (lane32 == 31) R = 0.f;                     // col 128 zero-pad
}

#define CONV4(o0, o1, o2, o3)                                                \
    float o0 = w_0*L0   + w_1*m0.x + w_2*m0.y                                \
             + w_3*L1   + w_4*m1.x + w_5*m1.y                                \
             + w_6*L2   + w_7*m2.x + w_8*m2.y;                               \
    float o1 = w_0*m0.x + w_1*m0.y + w_2*m0.z                                \
             + w_3*m1.x + w_4*m1.y + w_5*m1.z                                \
             + w_6*m2.x + w_7*m2.y + w_8*m2.z;                               \
    float o2 = w_0*m0.y + w_1*m0.z + w_2*m0.w                                \
             + w_3*m1.y + w_4*m1.z + w_5*m1.w                                \
             + w_6*m2.y + w_7*m2.z + w_8*m2.w;                               \
    float o3 = w_0*m0.z + w_1*m0.w + w_2*R0                                  \
             + w_3*m1.z + w_4*m1.w + w_5*R1                                  \
             + w_6*m2.z + w_7*m2.w + w_8*R2

#define SLIDE() do { m0 = m1; L0 = L1; R0 = R1; m1 = m2; L1 = L2; R1 = R2; } while (0)

// ---------------------------------------------------------------------------
// Kernel A: ONE streaming read of x computing, per plane:
//   plane mean (for attention), conv-sum, conv-sumsq (for folded inst-norm).
// Thread t: columns [4*(t&31), +4), row strip [16*(t>>5), +16), sliding
// 3-row register window.
// ---------------------------------------------------------------------------
__global__ __launch_bounds__(256, 8) void k_stats(const float* __restrict__ x,
                                                  const float* __restrict__ rw,
                                                  float* __restrict__ p,
                                                  float* __restrict__ cstats) {
    const int plane = blockIdx.x;
    const int ch = plane & 255;
    const float* xp = x + (size_t)plane * HW;
    const int lane32 = threadIdx.x & 31;
    const int c4 = lane32 * 4;
    const int r0 = (threadIdx.x >> 5) * 16;

    const float w_0 = rw[ch*9+0], w_1 = rw[ch*9+1], w_2 = rw[ch*9+2];
    const float w_3 = rw[ch*9+3], w_4 = rw[ch*9+4], w_5 = rw[ch*9+5];
    const float w_6 = rw[ch*9+6], w_7 = rw[ch*9+7], w_8 = rw[ch*9+8];

    float4 m0, m1, m2;
    float L0, R0, L1, R1, L2, R2;
    load_row(xp, r0 - 1, c4, lane32, m0, L0, R0);
    load_row(xp, r0,     c4, lane32, m1, L1, R1);

    float xs = 0.f, s = 0.f, sq = 0.f;
#pragma unroll 4
    for (int j = 0; j < 16; ++j) {
        load_row(xp, r0 + j + 1, c4, lane32, m2, L2, R2);
        CONV4(o0, o1, o2, o3);
        s  += (o0 + o1) + (o2 + o3);
        sq += o0*o0 + o1*o1 + o2*o2 + o3*o3;
        xs += (m1.x + m1.y) + (m1.z + m1.w);   // row r counted exactly once
        SLIDE();
    }

#pragma unroll
    for (int off = 32; off; off >>= 1) {
        xs += __shfl_down(xs, off, 64);
        s  += __shfl_down(s,  off, 64);
        sq += __shfl_down(sq, off, 64);
    }
    __shared__ float red[12];
    const int wave = threadIdx.x >> 6, lane = threadIdx.x & 63;
    if (lane == 0) { red[wave] = xs; red[4+wave] = s; red[8+wave] = sq; }
    __syncthreads();
    if (threadIdx.x == 0) {
        p[plane]            = ((red[0]+red[1]) + (red[2]+red[3])) * (1.f/(float)HW);
        cstats[plane*2]     = (red[4]+red[5]) + (red[6]+red[7]);
        cstats[plane*2 + 1] = (red[8]+red[9]) + (red[10]+red[11]);
    }
}

// ---------------------------------------------------------------------------
// Kernel B: attention MLP (tiny, per-block) + conv + folded instance-norm +
// leaky, single streaming pass (x should be L2/L3-resident from kernel A).
//   out = a*(conv - mean_c) * rsqrt(a^2*var_c + eps); bias cancels exactly.
// ---------------------------------------------------------------------------
__global__ __launch_bounds__(256, 8) void k_out(const float* __restrict__ x,
                                                const float* __restrict__ w1,
                                                const float* __restrict__ w2,
                                                const float* __restrict__ rw,
                                                const float* __restrict__ p,
                                                const float* __restrict__ cstats,
                                                float* __restrict__ out) {
    __shared__ float hs[64];
    __shared__ float sh_mean, sh_scale;
    const int plane = blockIdx.x;
    const int b = plane >> 8, ch = plane & 255;

    // attention hidden layer: hs[j] = leaky(dot(p[b,:], w1[j,:])), 4 thr/j
    {
        const int j = threadIdx.x >> 2, part = threadIdx.x & 3;
        const float4* pr = (const float4*)(p  + b * 256 + part * 64);
        const float4* wr = (const float4*)(w1 + j * 256 + part * 64);
        float acc = 0.f;
#pragma unroll
        for (int k = 0; k < 16; ++k) {
            float4 pv = pr[k], wv = wr[k];
            acc += pv.x*wv.x + pv.y*wv.y + pv.z*wv.z + pv.w*wv.w;
        }
        acc += __shfl_xor(acc, 1, 64);
        acc += __shfl_xor(acc, 2, 64);
        if (part == 0) hs[j] = acc > 0.f ? acc : SLOPE * acc;
    }
    __syncthreads();
    if (threadIdx.x < 64) {
        float v = w2[ch * 64 + threadIdx.x] * hs[threadIdx.x];
#pragma unroll
        for (int off = 32; off; off >>= 1) v += __shfl_down(v, off, 64);
        if (threadIdx.x == 0) {
            const float a  = 1.f / (1.f + expf(-v));
            const float mc = cstats[plane*2] * (1.f/(float)HW);
            const float vc = cstats[plane*2 + 1] * (1.f/(float)HW) - mc * mc;
            sh_mean  = mc;
            sh_scale = a * rsqrtf(a * a * vc + EPS);
        }
    }

    const float w_0 = rw[ch*9+0], w_1 = rw[ch*9+1], w_2 = rw[ch*9+2];
    const float w_3 = rw[ch*9+3], w_4 = rw[ch*9+4], w_5 = rw[ch*9+5];
    const float w_6 = rw[ch*9+6], w_7 = rw[ch*9+7], w_8 = rw[ch*9+8];

    __syncthreads();
    const float mean_c = sh_mean, scale = sh_scale;

    const float* xp = x + (size_t)plane * HW;
    float* op = out + (size_t)plane * HW;
    const int lane32 = threadIdx.x & 31;
    const int c4 = lane32 * 4;
    const int r0 = (threadIdx.x >> 5) * 16;

    float4 m0, m1, m2;
    float L0, R0, L1, R1, L2, R2;
    load_row(xp, r0 - 1, c4, lane32, m0, L0, R0);
    load_row(xp, r0,     c4, lane32, m1, L1, R1);

#pragma unroll 4
    for (int j = 0; j < 16; ++j) {
        load_row(xp, r0 + j + 1, c4, lane32, m2, L2, R2);
        CONV4(o0, o1, o2, o3);
        v4f res;
        float t0 = scale * (o0 - mean_c); res.x = t0 > 0.f ? t0 : SLOPE * t0;
        float t1 = scale * (o1 - mean_c); res.y = t1 > 0.f ? t1 : SLOPE * t1;
        float t2 = scale * (o2 - mean_c); res.z = t2 > 0.f ? t2 : SLOPE * t2;
        float t3 = scale * (o3 - mean_c); res.w = t3 > 0.f ? t3 : SLOPE * t3;
        __builtin_nontemporal_store(res, (v4f*)(op + (r0 + j) * WW + c4));
        SLIDE();
    }
}

// ---------------------------------------------------------------------------
extern "C" void kernel_launch(void* const* d_in, const int* in_sizes, int n_in,
                              void* d_out, int out_size, void* d_ws, size_t ws_size,
                              hipStream_t stream) {
    const float* x  = (const float*)d_in[0];
    const float* w1 = (const float*)d_in[1];   // [64,256]
    const float* w2 = (const float*)d_in[2];   // [256,64]
    const float* rw = (const float*)d_in[3];   // [256,1,3,3]
    // d_in[4] (refine_b) cancels exactly in instance norm -- unused.
    float* out = (float*)d_out;

    float* p      = (float*)d_ws;       // 2048 floats
    float* cstats = p + NPLANE;         // 4096 floats (sum, sumsq per plane)

    k_stats<<<NPLANE, 256, 0, stream>>>(x, rw, p, cstats);
    k_out  <<<NPLANE, 256, 0, stream>>>(x, w1, w2, rw, p, cstats, out);
}